// Round 4
// baseline (287.967 us; speedup 1.0000x reference)
//
#include <hip/hip_runtime.h>

#define B_ 16
#define D_ 128
#define T_ 4096
#define C_ 1024
#define N_ (B_*T_)

// ---------------- init: zero used-flags + loss accumulator ----------------
__global__ __launch_bounds__(256) void vq_init_kernel(float* used, float* accum) {
    int tid = blockIdx.x * 256 + threadIdx.x;
    if (tid < C_) used[tid] = 0.0f;
    if (tid == 0) accum[0] = 0.0f;
}

// ---------------- e2[c] = ||embed_c||^2, numpy pairwise-8 replica ----------------
__global__ __launch_bounds__(256) void vq_e2_kernel(const float* __restrict__ embed,
                                                    float* __restrict__ e2) {
#pragma clang fp contract(off)
    int c = blockIdx.x * 256 + threadIdx.x;
    const float* row = embed + (size_t)c * D_;
    float r[8];
#pragma unroll
    for (int j = 0; j < 8; ++j) { float v = row[j]; r[j] = v * v; }
    for (int i = 8; i < D_; i += 8) {
#pragma unroll
        for (int j = 0; j < 8; ++j) { float v = row[i + j]; r[j] = r[j] + v * v; }
    }
    e2[c] = ((r[0] + r[1]) + (r[2] + r[3])) + ((r[4] + r[5]) + (r[6] + r[7]));
}

// ---------------- main scoring/argmin kernel (bit-replicates np fp32 d2) ----------------
// Block: 256 threads = 64 points x (16 code-lanes). 16 chunks of 64 codes.
__global__ __launch_bounds__(256) void vq_argmin_kernel(
    const float* __restrict__ x, const float* __restrict__ embed,
    const float* __restrict__ e2, float* __restrict__ idx_f,
    int* __restrict__ idx_i)
{
    __shared__ float xs[D_][64];   // x tile, transposed [d][point]
    __shared__ float es[D_][64];   // embed chunk, transposed [d][code]
    __shared__ float xxs[64];      // np-replica ||x||^2 per point

    const int g  = blockIdx.x;         // 1024 blocks
    const int b  = g >> 6;             // 64 blocks per batch row (T/64)
    const int t0 = (g & 63) << 6;
    const int tid = threadIdx.x;

    const float* xb = x + (size_t)b * D_ * T_ + t0;

    // stage x tile: coalesced 64-wide rows per d
#pragma unroll
    for (int k = 0; k < 32; ++k) {
        int e = tid + 256 * k;      // 8192 elements
        int d = e >> 6, tt = e & 63;
        xs[d][tt] = xb[(size_t)d * T_ + tt];
    }
    __syncthreads();

    // xx[p] = np.sum(x*x) pairwise-8 replica (separate square + add roundings)
    if (tid < 64) {
#pragma clang fp contract(off)
        float r[8];
#pragma unroll
        for (int j = 0; j < 8; ++j) { float v = xs[j][tid]; r[j] = v * v; }
        for (int i = 8; i < D_; i += 8) {
#pragma unroll
            for (int j = 0; j < 8; ++j) { float v = xs[i + j][tid]; r[j] = r[j] + v * v; }
        }
        xxs[tid] = ((r[0] + r[1]) + (r[2] + r[3])) + ((r[4] + r[5]) + (r[6] + r[7]));
    }

    const int tp = tid >> 4;   // 0..15 -> 4 points each
    const int tc = tid & 15;   // 0..15 -> 4 codes each

    float minv[4];
    int   mini[4];
#pragma unroll
    for (int i = 0; i < 4; ++i) { minv[i] = 3.4e38f; mini[i] = 0; }

    for (int ch = 0; ch < C_ / 64; ++ch) {
        const int c0 = ch * 64;
        __syncthreads();   // protect es from previous iteration's readers (also covers xxs)
        // stage embed chunk transposed: es[d][c] = embed[c0+c][d]
#pragma unroll
        for (int k = 0; k < 8; ++k) {
            int e = tid + 256 * k;     // 2048 float4 groups
            int c = e & 63, dq = e >> 6;   // dq in 0..31
            float4 v = *reinterpret_cast<const float4*>(embed + (size_t)(c0 + c) * D_ + 4 * dq);
            es[4 * dq + 0][c] = v.x;
            es[4 * dq + 1][c] = v.y;
            es[4 * dq + 2][c] = v.z;
            es[4 * dq + 3][c] = v.w;
        }
        __syncthreads();

        // G accumulation: sequential ascending-d fp32 FMA chain (BLAS sgemm replica)
        float acc[4][4];
#pragma unroll
        for (int i = 0; i < 4; ++i)
#pragma unroll
            for (int j = 0; j < 4; ++j) acc[i][j] = 0.f;

        for (int d = 0; d < D_; ++d) {
            float4 xv = *reinterpret_cast<const float4*>(&xs[d][tp * 4]);
            float4 ev = *reinterpret_cast<const float4*>(&es[d][tc * 4]);
            float xr[4] = { xv.x, xv.y, xv.z, xv.w };
            float er[4] = { ev.x, ev.y, ev.z, ev.w };
#pragma unroll
            for (int i = 0; i < 4; ++i)
#pragma unroll
                for (int j = 0; j < 4; ++j)
                    acc[i][j] = fmaf(xr[i], er[j], acc[i][j]);
        }

        // np-replica final combine: fl( fl(xx - 2G) + ee ), argmin first-occurrence
#pragma unroll
        for (int i = 0; i < 4; ++i) {
            float xxv = xxs[tp * 4 + i];
#pragma unroll
            for (int j = 0; j < 4; ++j) {
                int c = c0 + tc * 4 + j;
                float s;
                {
#pragma clang fp contract(off)
                    s = (xxv - 2.0f * acc[i][j]) + e2[c];
                }
                if (s < minv[i]) { minv[i] = s; mini[i] = c; }   // strict < keeps lowest c
            }
        }
    }

    // reduce (min, idx) across the 16 code-lanes (contiguous 16-lane groups)
#pragma unroll
    for (int i = 0; i < 4; ++i) {
        float v = minv[i];
        int  ci = mini[i];
#pragma unroll
        for (int m = 8; m >= 1; m >>= 1) {
            float ov = __shfl_xor(v, m, 16);
            int   oc = __shfl_xor(ci, m, 16);
            if (ov < v || (ov == v && oc < ci)) { v = ov; ci = oc; }
        }
        if (tc == 0) {
            int n = g * 64 + tp * 4 + i;
            idx_i[n] = ci;
            idx_f[n] = (float)ci;
        }
    }
}

// ---------------- gather + loss partials + used-flags ----------------
__global__ __launch_bounds__(256) void vq_gather_kernel(
    const float* __restrict__ x, const float* __restrict__ embed,
    const int* __restrict__ idx_i, float* __restrict__ out_q,
    float* __restrict__ accum, float* __restrict__ used)
{
    __shared__ int sidx[64];
    __shared__ float red[256];

    const int g  = blockIdx.x;     // 1024 blocks
    const int b  = g >> 6;
    const int t0 = (g & 63) << 6;
    const int tid = threadIdx.x;

    if (tid < 64) {
        int ci = idx_i[g * 64 + tid];
        sidx[tid] = ci;
        used[ci] = 1.0f;           // concurrent identical stores: benign
    }
    __syncthreads();

    const float* xb = x     + (size_t)b * D_ * T_ + t0;
    float*       ob = out_q + (size_t)b * D_ * T_ + t0;

    float local = 0.f;
#pragma unroll
    for (int k = 0; k < 32; ++k) {
        int e = tid + 256 * k;
        int d = e >> 6, tt = e & 63;
        float q  = embed[(size_t)sidx[tt] * D_ + d];  // gathered, L2-resident
        float xv = xb[(size_t)d * T_ + tt];           // coalesced
        ob[(size_t)d * T_ + tt] = q;                  // coalesced
        float df = xv - q;
        local += df * df;
    }

    red[tid] = local;
    __syncthreads();
    for (int st = 128; st > 0; st >>= 1) {
        if (tid < st) red[tid] += red[tid + st];
        __syncthreads();
    }
    if (tid == 0) atomicAdd(accum, red[0]);
}

// ---------------- finalize loss + utilization ----------------
__global__ __launch_bounds__(256) void vq_final_kernel(
    const float* __restrict__ used, const float* __restrict__ accum,
    float* __restrict__ out_loss, float* __restrict__ out_util)
{
    __shared__ float red[256];
    int tid = threadIdx.x;
    float s = 0.f;
    for (int k = tid; k < C_; k += 256) s += used[k];
    red[tid] = s;
    __syncthreads();
    for (int st = 128; st > 0; st >>= 1) {
        if (tid < st) red[tid] += red[tid + st];
        __syncthreads();
    }
    if (tid == 0) {
        out_loss[0] = 2.0f * accum[0] / (float)((size_t)N_ * D_);
        out_util[0] = red[0] / (float)C_;
    }
}

extern "C" void kernel_launch(void* const* d_in, const int* in_sizes, int n_in,
                              void* d_out, int out_size, void* d_ws, size_t ws_size,
                              hipStream_t stream) {
    const float* x     = (const float*)d_in[0];
    const float* embed = (const float*)d_in[1];

    float* out      = (float*)d_out;
    float* out_q    = out;                              // 8388608
    float* idx_f    = out + (size_t)B_ * D_ * T_;       // 65536
    float* out_loss = idx_f + N_;                       // 1
    float* out_util = out_loss + 1;                     // 1

    float* ws    = (float*)d_ws;
    float* e2    = ws;                  // 1024
    float* used  = ws + C_;             // 1024
    int*   idx_i = (int*)(ws + 2 * C_); // 65536 ints
    float* accum = ws + 2 * C_ + N_;    // 1

    vq_init_kernel  <<<4, 256, 0, stream>>>(used, accum);
    vq_e2_kernel    <<<C_ / 256, 256, 0, stream>>>(embed, e2);
    vq_argmin_kernel<<<N_ / 64, 256, 0, stream>>>(x, embed, e2, idx_f, idx_i);
    vq_gather_kernel<<<N_ / 64, 256, 0, stream>>>(x, embed, idx_i, out_q, accum, used);
    vq_final_kernel <<<1, 256, 0, stream>>>(used, accum, out_loss, out_util);
}

// Round 5
// 146.202 us; speedup vs baseline: 1.9697x; 1.9697x over previous
//
#include <hip/hip_runtime.h>

#define B_ 16
#define D_ 128
#define T_ 4096
#define C_ 1024
#define N_ (B_*T_)
#define MARGIN 1e-3f

typedef __attribute__((ext_vector_type(8))) short short8;
typedef __attribute__((ext_vector_type(4))) float f32x4;
typedef unsigned int u32;
typedef unsigned short u16;

static __device__ __forceinline__ u16 bf16_rne(float f) {
    u32 u = __float_as_uint(f);
    u32 r = (u + 0x7fffu + ((u >> 16) & 1u)) >> 16;
    return (u16)r;
}
static __device__ __forceinline__ float bf16_to_f32(u16 h) {
    return __uint_as_float(((u32)h) << 16);
}
static __device__ __forceinline__ short8 as_short8(int4 v) {
    union { int4 i; short8 s; } u; u.i = v; return u.s;
}

// ---------------- init ----------------
__global__ __launch_bounds__(256) void vq_init_kernel(float* used, float* accum, int* nflag) {
    int tid = blockIdx.x * 256 + threadIdx.x;
    if (tid < C_) used[tid] = 0.0f;
    if (tid == 0) { accum[0] = 0.0f; nflag[0] = 0; }
}

// ---------------- e2[c] = ||embed_c||^2, numpy pairwise-8 replica ----------------
__global__ __launch_bounds__(256) void vq_e2_kernel(const float* __restrict__ embed,
                                                    float* __restrict__ e2) {
#pragma clang fp contract(off)
    int c = blockIdx.x * 256 + threadIdx.x;
    const float* row = embed + (size_t)c * D_;
    float r[8];
#pragma unroll
    for (int j = 0; j < 8; ++j) { float v = row[j]; r[j] = v * v; }
    for (int i = 8; i < D_; i += 8) {
#pragma unroll
        for (int j = 0; j < 8; ++j) { float v = row[i + j]; r[j] = r[j] + v * v; }
    }
    e2[c] = ((r[0] + r[1]) + (r[2] + r[3])) + ((r[4] + r[5]) + (r[6] + r[7]));
}

// ---------------- pre-split embed into bf16 hi/lo (flat [c][d] pairs) ----------------
__global__ __launch_bounds__(256) void vq_esplit_kernel(const float* __restrict__ embed,
                                                        u32* __restrict__ e_hi,
                                                        u32* __restrict__ e_lo) {
    int i = blockIdx.x * 256 + threadIdx.x;    // pair index, C_*D_/2 = 65536 total
    float2 v = reinterpret_cast<const float2*>(embed)[i];
    u16 h0 = bf16_rne(v.x), h1 = bf16_rne(v.y);
    float l0 = v.x - bf16_to_f32(h0), l1 = v.y - bf16_to_f32(h1);
    u16 g0 = bf16_rne(l0), g1 = bf16_rne(l1);
    e_hi[i] = (u32)h0 | ((u32)h1 << 16);
    e_lo[i] = (u32)g0 | ((u32)g1 << 16);
}

// ---------------- MFMA prefilter argmin ----------------
// 1024 blocks x 256 thr (4 waves). Block = 64 points; wave w covers codes
// {rnd*64 + w*16 .. +15} for rnd=0..15. A = e chunk (16 codes x 32 dims),
// B = x strip (32 dims x 16 points), 3 split MFMAs per K-step.
__global__ __launch_bounds__(256) void vq_mfma_kernel(
    const float* __restrict__ x, const u32* __restrict__ e_hi, const u32* __restrict__ e_lo,
    const float* __restrict__ e2, float* __restrict__ idx_f, int* __restrict__ idx_i,
    int* __restrict__ flagged, int* __restrict__ nflag)
{
    __shared__ int4  ebuf[2048];     // [0..1023] hi (16KB), [1024..2047] lo (16KB), swizzled
    __shared__ float ee_s[C_];       // 4KB
    __shared__ float mv1[4][64];
    __shared__ int   mi1[4][64];
    __shared__ float mv2[4][64];

    const int g  = blockIdx.x;
    const int b  = g >> 6;
    const int t0 = (g & 63) << 6;
    const int tid = threadIdx.x;
    const int w  = tid >> 6;      // wave 0..3
    const int l  = tid & 63;
    const int r  = l & 15;        // point col / code row within tile
    const int q  = l >> 4;        // k-group

    // stage ee (e2) to LDS; first in-loop barrier covers visibility
#pragma unroll
    for (int k = 0; k < 4; ++k) ee_s[tid + 256 * k] = e2[tid + 256 * k];

    // ---- gather x fragments into registers (one-time) ----
    // strip s: points t0+16s+r ; kstep t: dims 32t + 8q + j
    short8 xh[4][4], xl[4][4];
    {
        const float* xb = x + (size_t)b * ((size_t)D_ * T_) + t0 + r;
#pragma unroll
        for (int s = 0; s < 4; ++s) {
            const float* xp = xb + 16 * s;
#pragma unroll
            for (int t = 0; t < 4; ++t) {
                float f[8];
#pragma unroll
                for (int j = 0; j < 8; ++j)
                    f[j] = xp[(size_t)(32 * t + 8 * q + j) * T_];
                u32 hw[4], lw[4];
#pragma unroll
                for (int j2 = 0; j2 < 4; ++j2) {
                    u32 hp;
                    asm("v_cvt_pk_bf16_f32 %0, %1, %2" : "=v"(hp) : "v"(f[2*j2]), "v"(f[2*j2+1]));
                    float r0 = f[2*j2]   - __uint_as_float(hp << 16);
                    float r1 = f[2*j2+1] - __uint_as_float(hp & 0xffff0000u);
                    u32 lp;
                    asm("v_cvt_pk_bf16_f32 %0, %1, %2" : "=v"(lp) : "v"(r0), "v"(r1));
                    hw[j2] = hp; lw[j2] = lp;
                }
                xh[s][t] = as_short8(make_int4((int)hw[0], (int)hw[1], (int)hw[2], (int)hw[3]));
                xl[s][t] = as_short8(make_int4((int)lw[0], (int)lw[1], (int)lw[2], (int)lw[3]));
            }
        }
    }

    float rv1[4], rv2[4];
    int   ri1[4];
#pragma unroll
    for (int s = 0; s < 4; ++s) { rv1[s] = 3.4e38f; rv2[s] = 3.4e38f; ri1[s] = 0; }

    for (int rnd = 0; rnd < 16; ++rnd) {
        const int cbase = rnd * 64;
        // ---- stage e chunk: 64 codes x 128 dims, hi+lo, swizzled via pre-swizzled src ----
        // LDS byte a (within 16KB buf): content = e_flat[cbase*256 + (a ^ ((code&7)<<4))]
#pragma unroll
        for (int i = 0; i < 4; ++i) {
            int chunk = w * 4 + i;               // 0..15 (1KB chunks)
            int a = chunk * 1024 + l * 16;       // this lane's LDS byte
            int ec = a >> 8;                     // code row in buffer
            int src_off = (a ^ ((ec & 7) << 4)) >> 2;   // u32 index
            __builtin_amdgcn_global_load_lds(
                (const __attribute__((address_space(1))) u32*)(e_hi + cbase * 64 + src_off),
                (__attribute__((address_space(3))) u32*)&ebuf[chunk * 64], 16, 0, 0);
            __builtin_amdgcn_global_load_lds(
                (const __attribute__((address_space(1))) u32*)(e_lo + cbase * 64 + src_off),
                (__attribute__((address_space(3))) u32*)&ebuf[1024 + chunk * 64], 16, 0, 0);
        }
        asm volatile("s_waitcnt vmcnt(0)" ::: "memory");
        __syncthreads();

        // ---- A-frags: e codes ec = w*16 + r ; dblk = 4t + q (swizzled read) ----
        short8 eh[4], el[4];
        {
            const int ec = w * 16 + r;
#pragma unroll
            for (int t = 0; t < 4; ++t) {
                int idx4 = ec * 16 + ((4 * t + q) ^ (ec & 7));
                eh[t] = as_short8(ebuf[idx4]);
                el[t] = as_short8(ebuf[1024 + idx4]);
            }
        }

        f32x4 eev = *reinterpret_cast<const f32x4*>(&ee_s[cbase + w * 16 + 4 * q]);

#pragma unroll
        for (int s = 0; s < 4; ++s) {
            f32x4 acc = {0.f, 0.f, 0.f, 0.f};
#pragma unroll
            for (int t = 0; t < 4; ++t) {
                acc = __builtin_amdgcn_mfma_f32_16x16x32_bf16(eh[t], xh[s][t], acc, 0, 0, 0);
                acc = __builtin_amdgcn_mfma_f32_16x16x32_bf16(el[t], xh[s][t], acc, 0, 0, 0);
                acc = __builtin_amdgcn_mfma_f32_16x16x32_bf16(eh[t], xl[s][t], acc, 0, 0, 0);
            }
            // D: col = l&15 -> point 16s+r ; row = 4q+reg -> code cbase + w*16 + 4q + reg
#pragma unroll
            for (int reg = 0; reg < 4; ++reg) {
                float sc = fmaf(-2.0f, acc[reg], eev[reg]);
                int c = cbase + w * 16 + 4 * q + reg;
                if (sc < rv1[s]) { rv2[s] = rv1[s]; rv1[s] = sc; ri1[s] = c; }
                else rv2[s] = fminf(rv2[s], sc);
            }
        }
        __syncthreads();   // done reading ebuf before next stage
    }

    // ---- merge across the 4 lane-groups (codes) per strip ----
#pragma unroll
    for (int s = 0; s < 4; ++s) {
        float v1 = rv1[s], v2 = rv2[s];
        int   i1 = ri1[s];
#pragma unroll
        for (int mo = 0; mo < 2; ++mo) {
            int m = 16 << mo;
            float ov1 = __shfl_xor(v1, m, 64);
            int   oi1 = __shfl_xor(i1, m, 64);
            float ov2 = __shfl_xor(v2, m, 64);
            float nv2 = fminf(fmaxf(v1, ov1), fminf(v2, ov2));
            if (ov1 < v1 || (ov1 == v1 && oi1 < i1)) { v1 = ov1; i1 = oi1; }
            v2 = nv2;
        }
        if (q == 0) { mv1[w][16 * s + r] = v1; mi1[w][16 * s + r] = i1; mv2[w][16 * s + r] = v2; }
    }
    __syncthreads();

    // ---- merge across waves; write provisional idx; flag near-ties ----
    if (tid < 64) {
        float V1 = 3.4e38f, V2 = 3.4e38f;
        int   I1 = 0;
#pragma unroll
        for (int w2 = 0; w2 < 4; ++w2) {
            float a1 = mv1[w2][tid]; int ai = mi1[w2][tid]; float a2 = mv2[w2][tid];
            if (a1 < V1 || (a1 == V1 && ai < I1)) { V2 = fminf(V2, V1); V1 = a1; I1 = ai; }
            else V2 = fminf(V2, a1);
            V2 = fminf(V2, a2);
        }
        int n = g * 64 + tid;
        idx_i[n] = I1;
        idx_f[n] = (float)I1;
        if (V2 - V1 < MARGIN) { int pos = atomicAdd(nflag, 1); flagged[pos] = n; }
    }
}

// ---------------- exact numpy-replica rescore of flagged points ----------------
__global__ __launch_bounds__(256) void vq_refine_kernel(
    const float* __restrict__ x, const float* __restrict__ embed,
    const float* __restrict__ e2,
    const int* __restrict__ flagged, const int* __restrict__ nflag,
    float* __restrict__ idx_f, int* __restrict__ idx_i)
{
    __shared__ float xs[D_];
    __shared__ float xx_s;
    __shared__ float rv[256];
    __shared__ int   ri[256];

    const int tid = threadIdx.x;
    const int total = *nflag;

    for (int fi = blockIdx.x; fi < total; fi += gridDim.x) {
        __syncthreads();
        int n = flagged[fi];
        int b = n >> 12;
        int t = n & (T_ - 1);
        if (tid < D_) xs[tid] = x[(size_t)b * ((size_t)D_ * T_) + (size_t)tid * T_ + t];
        __syncthreads();
        if (tid == 0) {
            float r8[8];
            {
#pragma clang fp contract(off)
                for (int j = 0; j < 8; ++j) { float v = xs[j]; r8[j] = v * v; }
                for (int i = 8; i < D_; i += 8)
                    for (int j = 0; j < 8; ++j) { float v = xs[i + j]; r8[j] = r8[j] + v * v; }
                xx_s = ((r8[0] + r8[1]) + (r8[2] + r8[3])) + ((r8[4] + r8[5]) + (r8[6] + r8[7]));
            }
        }
        __syncthreads();
        float xx = xx_s;
        float bestv = 3.4e38f;
        int   besti = 0;
        for (int k = 0; k < 4; ++k) {
            int c = tid + 256 * k;
            const float* er = embed + (size_t)c * D_;
            float acc = 0.f;
            for (int d = 0; d < D_; ++d) acc = fmaf(xs[d], er[d], acc);
            float s;
            {
#pragma clang fp contract(off)
                s = (xx - 2.0f * acc) + e2[c];
            }
            if (s < bestv) { bestv = s; besti = c; }   // ascending c, strict < keeps lowest
        }
        rv[tid] = bestv; ri[tid] = besti;
        __syncthreads();
        for (int st = 128; st > 0; st >>= 1) {
            if (tid < st) {
                float ov = rv[tid + st]; int oi = ri[tid + st];
                if (ov < rv[tid] || (ov == rv[tid] && oi < ri[tid])) { rv[tid] = ov; ri[tid] = oi; }
            }
            __syncthreads();
        }
        if (tid == 0) { idx_i[n] = ri[0]; idx_f[n] = (float)ri[0]; }
    }
}

// ---------------- gather + loss partials + used-flags ----------------
__global__ __launch_bounds__(256) void vq_gather_kernel(
    const float* __restrict__ x, const float* __restrict__ embed,
    const int* __restrict__ idx_i, float* __restrict__ out_q,
    float* __restrict__ accum, float* __restrict__ used)
{
    __shared__ int sidx[64];
    __shared__ float red[256];

    const int g  = blockIdx.x;
    const int b  = g >> 6;
    const int t0 = (g & 63) << 6;
    const int tid = threadIdx.x;

    if (tid < 64) {
        int ci = idx_i[g * 64 + tid];
        sidx[tid] = ci;
        used[ci] = 1.0f;
    }
    __syncthreads();

    const float* xb = x     + (size_t)b * ((size_t)D_ * T_) + t0;
    float*       ob = out_q + (size_t)b * ((size_t)D_ * T_) + t0;

    float local = 0.f;
#pragma unroll
    for (int k = 0; k < 32; ++k) {
        int e = tid + 256 * k;
        int d = e >> 6, tt = e & 63;
        float qv = embed[(size_t)sidx[tt] * D_ + d];
        float xv = xb[(size_t)d * T_ + tt];
        ob[(size_t)d * T_ + tt] = qv;
        float df = xv - qv;
        local += df * df;
    }

    red[tid] = local;
    __syncthreads();
    for (int st = 128; st > 0; st >>= 1) {
        if (tid < st) red[tid] += red[tid + st];
        __syncthreads();
    }
    if (tid == 0) atomicAdd(accum, red[0]);
}

// ---------------- finalize ----------------
__global__ __launch_bounds__(256) void vq_final_kernel(
    const float* __restrict__ used, const float* __restrict__ accum,
    float* __restrict__ out_loss, float* __restrict__ out_util)
{
    __shared__ float red[256];
    int tid = threadIdx.x;
    float s = 0.f;
    for (int k = tid; k < C_; k += 256) s += used[k];
    red[tid] = s;
    __syncthreads();
    for (int st = 128; st > 0; st >>= 1) {
        if (tid < st) red[tid] += red[tid + st];
        __syncthreads();
    }
    if (tid == 0) {
        out_loss[0] = 2.0f * accum[0] / (float)((size_t)N_ * D_);
        out_util[0] = red[0] / (float)C_;
    }
}

extern "C" void kernel_launch(void* const* d_in, const int* in_sizes, int n_in,
                              void* d_out, int out_size, void* d_ws, size_t ws_size,
                              hipStream_t stream) {
    const float* x     = (const float*)d_in[0];
    const float* embed = (const float*)d_in[1];

    float* out      = (float*)d_out;
    float* out_q    = out;                              // 8388608
    float* idx_f    = out + (size_t)B_ * D_ * T_;       // 65536
    float* out_loss = idx_f + N_;                       // 1
    float* out_util = out_loss + 1;                     // 1

    float* ws      = (float*)d_ws;
    float* e2      = ws;                                 // [0 .. 1024)
    float* used    = ws + 1024;                          // [1024 .. 2048)
    int*   idx_i   = (int*)(ws + 2048);                  // [2048 .. 67584)
    float* accum   = ws + 67584;                         // [67584]
    int*   nflag   = (int*)(ws + 67585);                 // [67585]
    int*   flagged = (int*)(ws + 67588);                 // [67588 .. 133124)  (padded)
    u32*   e_hi    = (u32*)(ws + 133124);                // 65536 u32, 16B-aligned
    u32*   e_lo    = (u32*)(ws + 198660);                // 65536 u32

    vq_init_kernel  <<<4, 256, 0, stream>>>(used, accum, nflag);
    vq_e2_kernel    <<<C_ / 256, 256, 0, stream>>>(embed, e2);
    vq_esplit_kernel<<<C_ * D_ / 2 / 256, 256, 0, stream>>>(embed, e_hi, e_lo);
    vq_mfma_kernel  <<<N_ / 64, 256, 0, stream>>>(x, e_hi, e_lo, e2, idx_f, idx_i, flagged, nflag);
    vq_refine_kernel<<<256, 256, 0, stream>>>(x, embed, e2, flagged, nflag, idx_f, idx_i);
    vq_gather_kernel<<<N_ / 64, 256, 0, stream>>>(x, embed, idx_i, out_q, accum, used);
    vq_final_kernel <<<1, 256, 0, stream>>>(used, accum, out_loss, out_util);
}

// Round 7
// 129.676 us; speedup vs baseline: 2.2207x; 1.1274x over previous
//
#include <hip/hip_runtime.h>

#define B_ 16
#define D_ 128
#define T_ 4096
#define C_ 1024
#define N_ (B_*T_)
#define MARGIN 1e-3f

typedef __attribute__((ext_vector_type(8))) short short8;
typedef __attribute__((ext_vector_type(4))) float f32x4;
typedef unsigned int u32;
typedef unsigned short u16;

static __device__ __forceinline__ u16 bf16_rne(float f) {
    u32 u = __float_as_uint(f);
    u32 r = (u + 0x7fffu + ((u >> 16) & 1u)) >> 16;
    return (u16)r;
}
static __device__ __forceinline__ float bf16_to_f32(u16 h) {
    return __uint_as_float(((u32)h) << 16);
}
static __device__ __forceinline__ short8 as_short8(int4 v) {
    union { int4 i; short8 s; } u; u.i = v; return u.s;
}

// ---------------- init ----------------
__global__ __launch_bounds__(256) void vq_init_kernel(float* used, float* accum, int* nflag) {
    int tid = blockIdx.x * 256 + threadIdx.x;
    if (tid < C_) used[tid] = 0.0f;
    if (tid == 0) { accum[0] = 0.0f; nflag[0] = 0; }
}

// ---------------- e2[c] = ||embed_c||^2, numpy pairwise-8 replica ----------------
__global__ __launch_bounds__(256) void vq_e2_kernel(const float* __restrict__ embed,
                                                    float* __restrict__ e2) {
#pragma clang fp contract(off)
    int c = blockIdx.x * 256 + threadIdx.x;
    const float* row = embed + (size_t)c * D_;
    float r[8];
#pragma unroll
    for (int j = 0; j < 8; ++j) { float v = row[j]; r[j] = v * v; }
    for (int i = 8; i < D_; i += 8) {
#pragma unroll
        for (int j = 0; j < 8; ++j) { float v = row[i + j]; r[j] = r[j] + v * v; }
    }
    e2[c] = ((r[0] + r[1]) + (r[2] + r[3])) + ((r[4] + r[5]) + (r[6] + r[7]));
}

// ---------------- pre-split embed into bf16 hi/lo + fp32 transpose eT[d][c] ----------------
__global__ __launch_bounds__(256) void vq_esplit_kernel(const float* __restrict__ embed,
                                                        u32* __restrict__ e_hi,
                                                        u32* __restrict__ e_lo,
                                                        float* __restrict__ eT) {
    int i = blockIdx.x * 256 + threadIdx.x;    // pair index, C_*D_/2 = 65536 total
    int c = i >> 6, d0 = (i & 63) * 2;
    float2 v = reinterpret_cast<const float2*>(embed)[i];
    u16 h0 = bf16_rne(v.x), h1 = bf16_rne(v.y);
    float l0 = v.x - bf16_to_f32(h0), l1 = v.y - bf16_to_f32(h1);
    u16 g0 = bf16_rne(l0), g1 = bf16_rne(l1);
    e_hi[i] = (u32)h0 | ((u32)h1 << 16);
    e_lo[i] = (u32)g0 | ((u32)g1 << 16);
    eT[(size_t)d0 * C_ + c]       = v.x;
    eT[(size_t)(d0 + 1) * C_ + c] = v.y;
}

// ---------------- MFMA prefilter argmin (3-term split, no LDS staging, no in-loop barriers) ----------------
// 1024 blocks x 4 waves. Block = 64 points; wave w covers codes {rnd*64 + w*16 .. +15}.
// A-frags (e) loaded global->reg from L2-resident e_hi/e_lo. 48 MFMA per wave-round.
__global__ __launch_bounds__(256) void vq_mfma_kernel(
    const float* __restrict__ x, const u32* __restrict__ e_hi, const u32* __restrict__ e_lo,
    const float* __restrict__ e2, float* __restrict__ idx_f, int* __restrict__ idx_i,
    int* __restrict__ flagged, int* __restrict__ nflag)
{
    __shared__ float mv1[4][64];
    __shared__ int   mi1[4][64];
    __shared__ float mv2[4][64];

    const int g  = blockIdx.x;
    const int b  = g >> 6;
    const int t0 = (g & 63) << 6;
    const int tid = threadIdx.x;
    const int w  = tid >> 6;      // wave 0..3
    const int l  = tid & 63;
    const int r  = l & 15;        // point col / code row within 16x16 tile
    const int q  = l >> 4;        // k-group

    // ---- x fragments (bf16 hi + lo residual), one-time gather ----
    // strip s: points t0+16s+r ; kstep t: dims 32t + 8q + j
    short8 xh[4][4], xl[4][4];
    {
        const float* xb = x + (size_t)b * ((size_t)D_ * T_) + t0 + r;
#pragma unroll
        for (int s = 0; s < 4; ++s) {
            const float* xp = xb + 16 * s;
#pragma unroll
            for (int t = 0; t < 4; ++t) {
                float f[8];
#pragma unroll
                for (int j = 0; j < 8; ++j)
                    f[j] = xp[(size_t)(32 * t + 8 * q + j) * T_];
                u32 hw[4], lw[4];
#pragma unroll
                for (int j2 = 0; j2 < 4; ++j2) {
                    u32 hp;
                    asm("v_cvt_pk_bf16_f32 %0, %1, %2" : "=v"(hp) : "v"(f[2*j2]), "v"(f[2*j2+1]));
                    float r0 = f[2*j2]   - __uint_as_float(hp << 16);
                    float r1 = f[2*j2+1] - __uint_as_float(hp & 0xffff0000u);
                    u32 lp;
                    asm("v_cvt_pk_bf16_f32 %0, %1, %2" : "=v"(lp) : "v"(r0), "v"(r1));
                    hw[j2] = hp; lw[j2] = lp;
                }
                xh[s][t] = as_short8(make_int4((int)hw[0], (int)hw[1], (int)hw[2], (int)hw[3]));
                xl[s][t] = as_short8(make_int4((int)lw[0], (int)lw[1], (int)lw[2], (int)lw[3]));
            }
        }
    }

    float rv1[4], rv2[4];
    int   ri1[4];
#pragma unroll
    for (int s = 0; s < 4; ++s) { rv1[s] = 3.4e38f; rv2[s] = 3.4e38f; ri1[s] = 0; }

    // per-lane e-frag base: code ec = w*16 + r, dims 8q.. ; u32 index = ec*64 + 16t + 4q
    const u32* ehp = e_hi + (size_t)(w * 16 + r) * 64 + 4 * q;
    const u32* elp = e_lo + (size_t)(w * 16 + r) * 64 + 4 * q;

    for (int rnd = 0; rnd < 16; ++rnd) {
        int4 eh4[4], el4[4];
#pragma unroll
        for (int t = 0; t < 4; ++t) {
            eh4[t] = *reinterpret_cast<const int4*>(ehp + 16 * t);
            el4[t] = *reinterpret_cast<const int4*>(elp + 16 * t);
        }
        ehp += 4096; elp += 4096;

        f32x4 eev = *reinterpret_cast<const f32x4*>(e2 + rnd * 64 + w * 16 + 4 * q);

#pragma unroll
        for (int s = 0; s < 4; ++s) {
            f32x4 acc = {0.f, 0.f, 0.f, 0.f};
#pragma unroll
            for (int t = 0; t < 4; ++t) {
                acc = __builtin_amdgcn_mfma_f32_16x16x32_bf16(as_short8(eh4[t]), xh[s][t], acc, 0, 0, 0);
                acc = __builtin_amdgcn_mfma_f32_16x16x32_bf16(as_short8(el4[t]), xh[s][t], acc, 0, 0, 0);
                acc = __builtin_amdgcn_mfma_f32_16x16x32_bf16(as_short8(eh4[t]), xl[s][t], acc, 0, 0, 0);
            }
            // D: col = l&15 -> point 16s+r ; row = 4q+reg -> code rnd*64 + w*16 + 4q + reg
#pragma unroll
            for (int reg = 0; reg < 4; ++reg) {
                float sc = fmaf(-2.0f, acc[reg], eev[reg]);
                int c = rnd * 64 + w * 16 + 4 * q + reg;
                if (sc < rv1[s]) { rv2[s] = rv1[s]; rv1[s] = sc; ri1[s] = c; }
                else rv2[s] = fminf(rv2[s], sc);
            }
        }
    }

    // ---- merge across the 4 q-lane-groups per strip (within wave) ----
#pragma unroll
    for (int s = 0; s < 4; ++s) {
        float v1 = rv1[s], v2 = rv2[s];
        int   i1 = ri1[s];
#pragma unroll
        for (int mo = 0; mo < 2; ++mo) {
            int m = 16 << mo;
            float ov1 = __shfl_xor(v1, m, 64);
            int   oi1 = __shfl_xor(i1, m, 64);
            float ov2 = __shfl_xor(v2, m, 64);
            float nv2 = fminf(fmaxf(v1, ov1), fminf(v2, ov2));
            if (ov1 < v1 || (ov1 == v1 && oi1 < i1)) { v1 = ov1; i1 = oi1; }
            v2 = nv2;
        }
        if (q == 0) { mv1[w][16 * s + r] = v1; mi1[w][16 * s + r] = i1; mv2[w][16 * s + r] = v2; }
    }
    __syncthreads();

    // ---- merge across waves; write provisional idx; flag near-ties ----
    if (tid < 64) {
        float V1 = 3.4e38f, V2 = 3.4e38f;
        int   I1 = 0;
#pragma unroll
        for (int w2 = 0; w2 < 4; ++w2) {
            float a1 = mv1[w2][tid]; int ai = mi1[w2][tid]; float a2 = mv2[w2][tid];
            if (a1 < V1 || (a1 == V1 && ai < I1)) { V2 = fminf(V2, V1); V1 = a1; I1 = ai; }
            else V2 = fminf(V2, a1);
            V2 = fminf(V2, a2);
        }
        int n = g * 64 + tid;
        idx_i[n] = I1;
        idx_f[n] = (float)I1;
        if (V2 - V1 < MARGIN) { int pos = atomicAdd(nflag, 1); flagged[pos] = n; }
    }
}

// ---------------- exact numpy-replica rescore of flagged points ----------------
// Block per point; lane handles 4 codes c = w*256 + 64k + l via coalesced eT[d][c] reads.
__global__ __launch_bounds__(256) void vq_refine_kernel(
    const float* __restrict__ x, const float* __restrict__ eT,
    const float* __restrict__ e2,
    const int* __restrict__ flagged, const int* __restrict__ nflag,
    float* __restrict__ idx_f, int* __restrict__ idx_i)
{
    __shared__ float xs[D_];
    __shared__ float r8s[8];
    __shared__ float xxsh;
    __shared__ float wvv[4];
    __shared__ int   wvi[4];

    const int tid = threadIdx.x;
    const int wv_ = tid >> 6;
    const int l   = tid & 63;
    const int total = *nflag;

    for (int fi = blockIdx.x; fi < total; fi += gridDim.x) {
        __syncthreads();                       // guard LDS reuse across iterations
        int n = flagged[fi];
        int b = n >> 12;
        int t = n & (T_ - 1);
        if (tid < D_) xs[tid] = x[(size_t)b * ((size_t)D_ * T_) + (size_t)tid * T_ + t];
        __syncthreads();

        // xx = np.sum(x*x) pairwise-8 replica (8 parallel chains + exact tree)
        if (tid < 8) {
#pragma clang fp contract(off)
            float v0 = xs[tid];
            float rj = v0 * v0;
            for (int i = 8; i < D_; i += 8) { float v = xs[i + tid]; rj = rj + v * v; }
            r8s[tid] = rj;
        }
        __syncthreads();
        if (tid == 0) {
#pragma clang fp contract(off)
            xxsh = ((r8s[0] + r8s[1]) + (r8s[2] + r8s[3])) + ((r8s[4] + r8s[5]) + (r8s[6] + r8s[7]));
        }
        __syncthreads();
        const float xx = xxsh;

        // 4 independent ascending-d FMA chains per lane (bit-exact sgemm replica)
        float acc0 = 0.f, acc1 = 0.f, acc2 = 0.f, acc3 = 0.f;
        const float* ep = eT + wv_ * 256 + l;
        for (int d = 0; d < D_; ++d) {
            float xv = xs[d];
            const float* rowp = ep + (size_t)d * C_;
            acc0 = fmaf(xv, rowp[0],   acc0);
            acc1 = fmaf(xv, rowp[64],  acc1);
            acc2 = fmaf(xv, rowp[128], acc2);
            acc3 = fmaf(xv, rowp[192], acc3);
        }

        float best = 3.4e38f;
        int   bi = 0;
        float a4[4] = {acc0, acc1, acc2, acc3};
#pragma unroll
        for (int k = 0; k < 4; ++k) {
            int c = wv_ * 256 + 64 * k + l;
            float s;
            {
#pragma clang fp contract(off)
                s = (xx - 2.0f * a4[k]) + e2[c];
            }
            if (s < best) { best = s; bi = c; }    // ascending c within lane
        }
        // cross-lane (64) reduce with lowest-index tiebreak
#pragma unroll
        for (int m = 1; m <= 32; m <<= 1) {
            float ov = __shfl_xor(best, m, 64);
            int   oc = __shfl_xor(bi, m, 64);
            if (ov < best || (ov == best && oc < bi)) { best = ov; bi = oc; }
        }
        if (l == 0) { wvv[wv_] = best; wvi[wv_] = bi; }
        __syncthreads();
        if (tid == 0) {
            float V = wvv[0]; int I = wvi[0];
#pragma unroll
            for (int w2 = 1; w2 < 4; ++w2) {
                if (wvv[w2] < V || (wvv[w2] == V && wvi[w2] < I)) { V = wvv[w2]; I = wvi[w2]; }
            }
            idx_i[n] = I;
            idx_f[n] = (float)I;
        }
    }
}

// ---------------- gather + loss partials + used-flags ----------------
__global__ __launch_bounds__(256) void vq_gather_kernel(
    const float* __restrict__ x, const float* __restrict__ embed,
    const int* __restrict__ idx_i, float* __restrict__ out_q,
    float* __restrict__ accum, float* __restrict__ used)
{
    __shared__ int sidx[64];
    __shared__ float red[256];

    const int g  = blockIdx.x;
    const int b  = g >> 6;
    const int t0 = (g & 63) << 6;
    const int tid = threadIdx.x;

    if (tid < 64) {
        int ci = idx_i[g * 64 + tid];
        sidx[tid] = ci;
        used[ci] = 1.0f;
    }
    __syncthreads();

    const float* xb = x     + (size_t)b * ((size_t)D_ * T_) + t0;
    float*       ob = out_q + (size_t)b * ((size_t)D_ * T_) + t0;

    float local = 0.f;
#pragma unroll
    for (int k = 0; k < 32; ++k) {
        int e = tid + 256 * k;
        int d = e >> 6, tt = e & 63;
        float qv = embed[(size_t)sidx[tt] * D_ + d];
        float xv = xb[(size_t)d * T_ + tt];
        ob[(size_t)d * T_ + tt] = qv;
        float df = xv - qv;
        local += df * df;
    }

    red[tid] = local;
    __syncthreads();
    for (int st = 128; st > 0; st >>= 1) {
        if (tid < st) red[tid] += red[tid + st];
        __syncthreads();
    }
    if (tid == 0) atomicAdd(accum, red[0]);
}

// ---------------- finalize ----------------
__global__ __launch_bounds__(256) void vq_final_kernel(
    const float* __restrict__ used, const float* __restrict__ accum,
    float* __restrict__ out_loss, float* __restrict__ out_util)
{
    __shared__ float red[256];
    int tid = threadIdx.x;
    float s = 0.f;
    for (int k = tid; k < C_; k += 256) s += used[k];
    red[tid] = s;
    __syncthreads();
    for (int st = 128; st > 0; st >>= 1) {
        if (tid < st) red[tid] += red[tid + st];
        __syncthreads();
    }
    if (tid == 0) {
        out_loss[0] = 2.0f * accum[0] / (float)((size_t)N_ * D_);
        out_util[0] = red[0] / (float)C_;
    }
}

extern "C" void kernel_launch(void* const* d_in, const int* in_sizes, int n_in,
                              void* d_out, int out_size, void* d_ws, size_t ws_size,
                              hipStream_t stream) {
    const float* x     = (const float*)d_in[0];
    const float* embed = (const float*)d_in[1];

    float* out      = (float*)d_out;
    float* out_q    = out;                              // 8388608
    float* idx_f    = out + (size_t)B_ * D_ * T_;       // 65536
    float* out_loss = idx_f + N_;                       // 1
    float* out_util = out_loss + 1;                     // 1

    float* ws      = (float*)d_ws;
    float* e2      = ws;                                 // [0 .. 1024)
    float* used    = ws + 1024;                          // [1024 .. 2048)
    int*   idx_i   = (int*)(ws + 2048);                  // [2048 .. 67584)
    float* accum   = ws + 67584;                         // [67584]
    int*   nflag   = (int*)(ws + 67585);                 // [67585]
    int*   flagged = (int*)(ws + 67588);                 // [67588 .. 133124)
    u32*   e_hi    = (u32*)(ws + 133124);                // 65536 u32, 16B-aligned
    u32*   e_lo    = (u32*)(ws + 198660);                // 65536 u32, 16B-aligned
    float* eT      = ws + 264196;                        // 131072 f32, 16B-aligned

    vq_init_kernel  <<<4, 256, 0, stream>>>(used, accum, nflag);
    vq_e2_kernel    <<<C_ / 256, 256, 0, stream>>>(embed, e2);
    vq_esplit_kernel<<<C_ * D_ / 2 / 256, 256, 0, stream>>>(embed, e_hi, e_lo, eT);
    vq_mfma_kernel  <<<N_ / 64, 256, 0, stream>>>(x, e_hi, e_lo, e2, idx_f, idx_i, flagged, nflag);
    vq_refine_kernel<<<1024, 256, 0, stream>>>(x, eT, e2, flagged, nflag, idx_f, idx_i);
    vq_gather_kernel<<<N_ / 64, 256, 0, stream>>>(x, embed, idx_i, out_q, accum, used);
    vq_final_kernel <<<1, 256, 0, stream>>>(used, accum, out_loss, out_util);
}

// Round 8
// 113.024 us; speedup vs baseline: 2.5478x; 1.1473x over previous
//
#include <hip/hip_runtime.h>
#include <hip/hip_fp16.h>

#define B_ 16
#define D_ 128
#define T_ 4096
#define C_ 1024
#define N_ (B_*T_)
#define MARGIN 1.5e-3f

typedef __attribute__((ext_vector_type(8))) __fp16 fp16x8;
typedef __attribute__((ext_vector_type(4))) float f32x4;
typedef unsigned int u32;
typedef unsigned short u16;

static __device__ __forceinline__ fp16x8 as_fp16x8(int4 v) {
    union { int4 i; fp16x8 h; } u; u.i = v; return u.h;
}
static __device__ __forceinline__ u32 pack_h2(float a, float b) {
    return (u32)__half_as_ushort(__float2half(a)) |
           ((u32)__half_as_ushort(__float2half(b)) << 16);
}

// ---------------- init ----------------
__global__ __launch_bounds__(256) void vq_init_kernel(float* used, float* accum, int* nflag) {
    int tid = blockIdx.x * 256 + threadIdx.x;
    if (tid < C_) used[tid] = 0.0f;
    if (tid == 0) { accum[0] = 0.0f; nflag[0] = 0; }
}

// ---------------- e2[c] = ||embed_c||^2, numpy pairwise-8 replica ----------------
__global__ __launch_bounds__(256) void vq_e2_kernel(const float* __restrict__ embed,
                                                    float* __restrict__ e2) {
#pragma clang fp contract(off)
    int c = blockIdx.x * 256 + threadIdx.x;
    const float* row = embed + (size_t)c * D_;
    float r[8];
#pragma unroll
    for (int j = 0; j < 8; ++j) { float v = row[j]; r[j] = v * v; }
    for (int i = 8; i < D_; i += 8) {
#pragma unroll
        for (int j = 0; j < 8; ++j) { float v = row[i + j]; r[j] = r[j] + v * v; }
    }
    e2[c] = ((r[0] + r[1]) + (r[2] + r[3])) + ((r[4] + r[5]) + (r[6] + r[7]));
}

// ---------------- prep: split embed into fp16 hi/lo (wave-tile-major) + fp32 transpose eT ----------------
// epk layout (u32 units): chunk(rnd,w,t)=rnd*16+w*4+t ; index = chunk*256 + (q*16+r)*4 + j2
// content of (c, d2): c = rnd*64+w*16+r ; d2 = 16t+4q+j2   (d2 = dim-pair index)
__global__ __launch_bounds__(256) void vq_eprep_kernel(const float* __restrict__ embed,
                                                       u32* __restrict__ epk_hi,
                                                       u32* __restrict__ epk_lo,
                                                       float* __restrict__ eT) {
    int i = blockIdx.x * 256 + threadIdx.x;    // pair index, C_*D_/2 = 65536 total
    int c = i >> 6, d2 = i & 63;
    float2 v = reinterpret_cast<const float2*>(embed)[i];
    __half h0 = __float2half(v.x), h1 = __float2half(v.y);
    float l0 = v.x - __half2float(h0), l1 = v.y - __half2float(h1);
    u32 hp = (u32)__half_as_ushort(h0) | ((u32)__half_as_ushort(h1) << 16);
    u32 lp = (u32)__half_as_ushort(__float2half(l0)) |
             ((u32)__half_as_ushort(__float2half(l1)) << 16);
    int chunk = (c >> 6) * 16 + ((c >> 4) & 3) * 4 + (d2 >> 4);
    int oi = chunk * 256 + (((d2 >> 2) & 3) * 16 + (c & 15)) * 4 + (d2 & 3);
    epk_hi[oi] = hp;
    epk_lo[oi] = lp;
    int d0 = d2 * 2;
    eT[(size_t)d0 * C_ + c]       = v.x;
    eT[(size_t)(d0 + 1) * C_ + c] = v.y;
}

// ---------------- MFMA prefilter argmin (fp16 2-term, x-frags in LDS, coalesced e-loads) ----------------
// 1024 blocks x 4 waves. Block = 64 points; wave w covers codes {rnd*64 + w*16 .. +15}, rnd=0..15.
__global__ __launch_bounds__(256) void vq_mfma_kernel(
    const float* __restrict__ x, const u32* __restrict__ epk_hi, const u32* __restrict__ epk_lo,
    const float* __restrict__ e2, float* __restrict__ idx_f, int* __restrict__ idx_i,
    int* __restrict__ flagged, int* __restrict__ nflag)
{
    __shared__ int4  xb_lds[1024];   // 16KB: x fp16 frags, [(s*4+t)*64 + l]
    __shared__ float mv1[4][64];
    __shared__ int   mi1[4][64];
    __shared__ float mv2[4][64];

    const int g  = blockIdx.x;
    const int b  = g >> 6;
    const int t0 = (g & 63) << 6;
    const int tid = threadIdx.x;
    const int w  = tid >> 6;      // wave 0..3
    const int l  = tid & 63;
    const int r  = l & 15;        // point col / code row within 16x16 tile
    const int q  = l >> 4;        // k-group

    // ---- one-time: convert x block-tile to fp16 frags in LDS (cooperative, w acts as strip s) ----
    {
        const int s = w;
        const float* xp = x + (size_t)b * ((size_t)D_ * T_) + (t0 + 16 * s + r);
#pragma unroll
        for (int t = 0; t < 4; ++t) {
            float f[8];
#pragma unroll
            for (int j = 0; j < 8; ++j)
                f[j] = xp[(size_t)(32 * t + 8 * q + j) * T_];
            int4 pk;
            pk.x = (int)pack_h2(f[0], f[1]);
            pk.y = (int)pack_h2(f[2], f[3]);
            pk.z = (int)pack_h2(f[4], f[5]);
            pk.w = (int)pack_h2(f[6], f[7]);
            xb_lds[(s * 4 + t) * 64 + l] = pk;
        }
    }
    __syncthreads();

    float rv1[4], rv2[4];
    int   ri1[4];
#pragma unroll
    for (int s = 0; s < 4; ++s) { rv1[s] = 3.4e38f; rv2[s] = 3.4e38f; ri1[s] = 0; }

    // per-lane e base (u32): wave w chunk base = w*4*256, + l*4 within chunk
    const u32* ephi = epk_hi + w * 1024 + l * 4;
    const u32* eplo = epk_lo + w * 1024 + l * 4;

    for (int rnd = 0; rnd < 16; ++rnd) {
        int4 eh4[4], el4[4];
#pragma unroll
        for (int t = 0; t < 4; ++t) {
            eh4[t] = *reinterpret_cast<const int4*>(ephi + rnd * 4096 + t * 256);
            el4[t] = *reinterpret_cast<const int4*>(eplo + rnd * 4096 + t * 256);
        }
        f32x4 eev = *reinterpret_cast<const f32x4*>(e2 + rnd * 64 + w * 16 + 4 * q);

#pragma unroll
        for (int s = 0; s < 4; ++s) {
            f32x4 acc = {0.f, 0.f, 0.f, 0.f};
#pragma unroll
            for (int t = 0; t < 4; ++t) {
                fp16x8 xa = as_fp16x8(xb_lds[(s * 4 + t) * 64 + l]);
                acc = __builtin_amdgcn_mfma_f32_16x16x32_f16(as_fp16x8(eh4[t]), xa, acc, 0, 0, 0);
                acc = __builtin_amdgcn_mfma_f32_16x16x32_f16(as_fp16x8(el4[t]), xa, acc, 0, 0, 0);
            }
            // D: col = l&15 -> point 16s+r ; row = 4q+reg -> code rnd*64 + w*16 + 4q + reg
#pragma unroll
            for (int reg = 0; reg < 4; ++reg) {
                float sc = fmaf(-2.0f, acc[reg], eev[reg]);
                int c = rnd * 64 + w * 16 + 4 * q + reg;
                if (sc < rv1[s]) { rv2[s] = rv1[s]; rv1[s] = sc; ri1[s] = c; }
                else rv2[s] = fminf(rv2[s], sc);
            }
        }
    }

    // ---- merge across the 4 q-lane-groups per strip (within wave) ----
#pragma unroll
    for (int s = 0; s < 4; ++s) {
        float v1 = rv1[s], v2 = rv2[s];
        int   i1 = ri1[s];
#pragma unroll
        for (int mo = 0; mo < 2; ++mo) {
            int m = 16 << mo;
            float ov1 = __shfl_xor(v1, m, 64);
            int   oi1 = __shfl_xor(i1, m, 64);
            float ov2 = __shfl_xor(v2, m, 64);
            float nv2 = fminf(fmaxf(v1, ov1), fminf(v2, ov2));
            if (ov1 < v1 || (ov1 == v1 && oi1 < i1)) { v1 = ov1; i1 = oi1; }
            v2 = nv2;
        }
        if (q == 0) { mv1[w][16 * s + r] = v1; mi1[w][16 * s + r] = i1; mv2[w][16 * s + r] = v2; }
    }
    __syncthreads();

    // ---- merge across waves; write provisional idx; flag near-ties ----
    if (tid < 64) {
        float V1 = 3.4e38f, V2 = 3.4e38f;
        int   I1 = 0;
#pragma unroll
        for (int w2 = 0; w2 < 4; ++w2) {
            float a1 = mv1[w2][tid]; int ai = mi1[w2][tid]; float a2 = mv2[w2][tid];
            if (a1 < V1 || (a1 == V1 && ai < I1)) { V2 = fminf(V2, V1); V1 = a1; I1 = ai; }
            else V2 = fminf(V2, a1);
            V2 = fminf(V2, a2);
        }
        int n = g * 64 + tid;
        idx_i[n] = I1;
        idx_f[n] = (float)I1;
        if (V2 - V1 < MARGIN) { int pos = atomicAdd(nflag, 1); flagged[pos] = n; }
    }
}

// ---------------- exact numpy-replica rescore of flagged points ----------------
// Block per point; lane handles 4 codes c = w*256 + 64k + l via coalesced eT[d][c] reads.
__global__ __launch_bounds__(256) void vq_refine_kernel(
    const float* __restrict__ x, const float* __restrict__ eT,
    const float* __restrict__ e2,
    const int* __restrict__ flagged, const int* __restrict__ nflag,
    float* __restrict__ idx_f, int* __restrict__ idx_i)
{
    __shared__ float xs[D_];
    __shared__ float r8s[8];
    __shared__ float xxsh;
    __shared__ float wvv[4];
    __shared__ int   wvi[4];

    const int tid = threadIdx.x;
    const int wv_ = tid >> 6;
    const int l   = tid & 63;
    const int total = *nflag;

    for (int fi = blockIdx.x; fi < total; fi += gridDim.x) {
        __syncthreads();                       // guard LDS reuse across iterations
        int n = flagged[fi];
        int b = n >> 12;
        int t = n & (T_ - 1);
        if (tid < D_) xs[tid] = x[(size_t)b * ((size_t)D_ * T_) + (size_t)tid * T_ + t];
        __syncthreads();

        // xx = np.sum(x*x) pairwise-8 replica (8 parallel chains + exact tree)
        if (tid < 8) {
#pragma clang fp contract(off)
            float v0 = xs[tid];
            float rj = v0 * v0;
            for (int i = 8; i < D_; i += 8) { float v = xs[i + tid]; rj = rj + v * v; }
            r8s[tid] = rj;
        }
        __syncthreads();
        if (tid == 0) {
#pragma clang fp contract(off)
            xxsh = ((r8s[0] + r8s[1]) + (r8s[2] + r8s[3])) + ((r8s[4] + r8s[5]) + (r8s[6] + r8s[7]));
        }
        __syncthreads();
        const float xx = xxsh;

        // 4 independent ascending-d FMA chains per lane (bit-exact sgemm replica)
        float acc0 = 0.f, acc1 = 0.f, acc2 = 0.f, acc3 = 0.f;
        const float* ep = eT + wv_ * 256 + l;
        for (int d = 0; d < D_; ++d) {
            float xv = xs[d];
            const float* rowp = ep + (size_t)d * C_;
            acc0 = fmaf(xv, rowp[0],   acc0);
            acc1 = fmaf(xv, rowp[64],  acc1);
            acc2 = fmaf(xv, rowp[128], acc2);
            acc3 = fmaf(xv, rowp[192], acc3);
        }

        float best = 3.4e38f;
        int   bi = 0;
        float a4[4] = {acc0, acc1, acc2, acc3};
#pragma unroll
        for (int k = 0; k < 4; ++k) {
            int c = wv_ * 256 + 64 * k + l;
            float s;
            {
#pragma clang fp contract(off)
                s = (xx - 2.0f * a4[k]) + e2[c];
            }
            if (s < best) { best = s; bi = c; }    // ascending c within lane
        }
        // cross-lane (64) reduce with lowest-index tiebreak
#pragma unroll
        for (int m = 1; m <= 32; m <<= 1) {
            float ov = __shfl_xor(best, m, 64);
            int   oc = __shfl_xor(bi, m, 64);
            if (ov < best || (ov == best && oc < bi)) { best = ov; bi = oc; }
        }
        if (l == 0) { wvv[wv_] = best; wvi[wv_] = bi; }
        __syncthreads();
        if (tid == 0) {
            float V = wvv[0]; int I = wvi[0];
#pragma unroll
            for (int w2 = 1; w2 < 4; ++w2) {
                if (wvv[w2] < V || (wvv[w2] == V && wvi[w2] < I)) { V = wvv[w2]; I = wvi[w2]; }
            }
            idx_i[n] = I;
            idx_f[n] = (float)I;
        }
    }
}

// ---------------- gather + loss partials + used-flags ----------------
__global__ __launch_bounds__(256) void vq_gather_kernel(
    const float* __restrict__ x, const float* __restrict__ embed,
    const int* __restrict__ idx_i, float* __restrict__ out_q,
    float* __restrict__ accum, float* __restrict__ used)
{
    __shared__ int sidx[64];
    __shared__ float red[256];

    const int g  = blockIdx.x;
    const int b  = g >> 6;
    const int t0 = (g & 63) << 6;
    const int tid = threadIdx.x;

    if (tid < 64) {
        int ci = idx_i[g * 64 + tid];
        sidx[tid] = ci;
        used[ci] = 1.0f;
    }
    __syncthreads();

    const float* xb = x     + (size_t)b * ((size_t)D_ * T_) + t0;
    float*       ob = out_q + (size_t)b * ((size_t)D_ * T_) + t0;

    float local = 0.f;
#pragma unroll
    for (int k = 0; k < 32; ++k) {
        int e = tid + 256 * k;
        int d = e >> 6, tt = e & 63;
        float qv = embed[(size_t)sidx[tt] * D_ + d];
        float xv = xb[(size_t)d * T_ + tt];
        ob[(size_t)d * T_ + tt] = qv;
        float df = xv - qv;
        local += df * df;
    }

    red[tid] = local;
    __syncthreads();
    for (int st = 128; st > 0; st >>= 1) {
        if (tid < st) red[tid] += red[tid + st];
        __syncthreads();
    }
    if (tid == 0) atomicAdd(accum, red[0]);
}

// ---------------- finalize ----------------
__global__ __launch_bounds__(256) void vq_final_kernel(
    const float* __restrict__ used, const float* __restrict__ accum,
    float* __restrict__ out_loss, float* __restrict__ out_util)
{
    __shared__ float red[256];
    int tid = threadIdx.x;
    float s = 0.f;
    for (int k = tid; k < C_; k += 256) s += used[k];
    red[tid] = s;
    __syncthreads();
    for (int st = 128; st > 0; st >>= 1) {
        if (tid < st) red[tid] += red[tid + st];
        __syncthreads();
    }
    if (tid == 0) {
        out_loss[0] = 2.0f * accum[0] / (float)((size_t)N_ * D_);
        out_util[0] = red[0] / (float)C_;
    }
}

extern "C" void kernel_launch(void* const* d_in, const int* in_sizes, int n_in,
                              void* d_out, int out_size, void* d_ws, size_t ws_size,
                              hipStream_t stream) {
    const float* x     = (const float*)d_in[0];
    const float* embed = (const float*)d_in[1];

    float* out      = (float*)d_out;
    float* out_q    = out;                              // 8388608
    float* idx_f    = out + (size_t)B_ * D_ * T_;       // 65536
    float* out_loss = idx_f + N_;                       // 1
    float* out_util = out_loss + 1;                     // 1

    float* ws      = (float*)d_ws;
    float* e2      = ws;                                 // [0 .. 1024)
    float* used    = ws + 1024;                          // [1024 .. 2048)
    int*   idx_i   = (int*)(ws + 2048);                  // [2048 .. 67584)
    float* accum   = ws + 67584;                         // [67584]
    int*   nflag   = (int*)(ws + 67585);                 // [67585]
    int*   flagged = (int*)(ws + 67588);                 // [67588 .. 133124)
    u32*   epk_hi  = (u32*)(ws + 133124);                // 65536 u32, 16B-aligned
    u32*   epk_lo  = (u32*)(ws + 198660);                // 65536 u32, 16B-aligned
    float* eT      = ws + 264196;                        // 131072 f32, 16B-aligned

    vq_init_kernel  <<<4, 256, 0, stream>>>(used, accum, nflag);
    vq_e2_kernel    <<<C_ / 256, 256, 0, stream>>>(embed, e2);
    vq_eprep_kernel <<<C_ * D_ / 2 / 256, 256, 0, stream>>>(embed, epk_hi, epk_lo, eT);
    vq_mfma_kernel  <<<N_ / 64, 256, 0, stream>>>(x, epk_hi, epk_lo, e2, idx_f, idx_i, flagged, nflag);
    vq_refine_kernel<<<1024, 256, 0, stream>>>(x, eT, e2, flagged, nflag, idx_f, idx_i);
    vq_gather_kernel<<<N_ / 64, 256, 0, stream>>>(x, embed, idx_i, out_q, accum, used);
    vq_final_kernel <<<1, 256, 0, stream>>>(used, accum, out_loss, out_util);
}